// Round 1
// baseline (208.112 us; speedup 1.0000x reference)
//
#include <hip/hip_runtime.h>

#define NROWS 262144
#define NCOLS 128

__global__ __launch_bounds__(256) void ordinal_loss_kernel(
    const float* __restrict__ pred,
    const int*   __restrict__ tgt,
    float*       __restrict__ out)
{
    __shared__ int ssum;
    if (threadIdx.x == 0) ssum = 0;
    __syncthreads();

    const int lane = threadIdx.x & 63;
    const int half = lane >> 5;   // which row of the wave's row-pair
    const int sub  = lane & 31;   // lane within the 32-lane half
    const int gwave = (int)((blockIdx.x * blockDim.x + threadIdx.x) >> 6);
    const int nwave = (int)((gridDim.x * blockDim.x) >> 6);

    int acc = 0;
    for (int row0 = gwave * 2; row0 < NROWS; row0 += nwave * 2) {
        const int r = row0 + half;
        // lane covers columns sub*4 .. sub*4+3 ; wave reads 1024 contiguous bytes
        const float4 v = *reinterpret_cast<const float4*>(
            pred + (size_t)r * NCOLS + (size_t)sub * 4);

        // per-lane argmax (first-index on ties via strict >)
        float bv = v.x; int bi = sub * 4;
        if (v.y > bv) { bv = v.y; bi = sub * 4 + 1; }
        if (v.z > bv) { bv = v.z; bi = sub * 4 + 2; }
        if (v.w > bv) { bv = v.w; bi = sub * 4 + 3; }

        // 32-lane butterfly reduce (masks < 32 stay within each half)
        #pragma unroll
        for (int m = 1; m <= 16; m <<= 1) {
            float ov = __shfl_xor(bv, m);
            int   oi = __shfl_xor(bi, m);
            if (ov > bv || (ov == bv && oi < bi)) { bv = ov; bi = oi; }
        }

        if (sub == 0) {
            const int t = tgt[r];
            int d = bi - t; if (d < 0) d = -d;
            // snap-to-target when |p-t|<=1 -> contribution 0, else |p-t|
            acc += (d <= 1) ? 0 : d;
        }
    }

    if (sub == 0) atomicAdd(&ssum, acc);
    __syncthreads();
    if (threadIdx.x == 0)
        atomicAdd(out, (float)ssum * (1.0f / (float)NROWS));
}

extern "C" void kernel_launch(void* const* d_in, const int* in_sizes, int n_in,
                              void* d_out, int out_size, void* d_ws, size_t ws_size,
                              hipStream_t stream) {
    const float* pred = (const float*)d_in[0];
    const int*   tgt  = (const int*)d_in[1];
    float* out = (float*)d_out;

    // d_out is poisoned 0xAA before every timed launch -> zero it first
    hipMemsetAsync(out, 0, sizeof(float), stream);

    // memory-bound: cap grid at ~2048 blocks, grid-stride the rest
    const int threads = 256;
    const int blocks  = 2048;
    ordinal_loss_kernel<<<blocks, threads, 0, stream>>>(pred, tgt, out);
}

// Round 2
// 203.879 us; speedup vs baseline: 1.0208x; 1.0208x over previous
//
#include <hip/hip_runtime.h>

#define NROWS 262144
#define NCOLS 128

__global__ __launch_bounds__(256) void ordinal_loss_kernel(
    const float* __restrict__ pred,
    const int*   __restrict__ tgt,
    float*       __restrict__ out)
{
    __shared__ int ssum;
    if (threadIdx.x == 0) ssum = 0;
    __syncthreads();

    const int lane = threadIdx.x & 63;
    const int half = lane >> 5;   // which row of the wave's row-pair
    const int sub  = lane & 31;   // lane within the 32-lane half
    const int gwave = (int)((blockIdx.x * blockDim.x + threadIdx.x) >> 6);
    const int nwave = (int)((gridDim.x * blockDim.x) >> 6);

    int acc = 0;
    // two rows per wave per iteration; unroll 2 -> two loads in flight
    #pragma unroll 2
    for (int row0 = gwave * 2; row0 < NROWS; row0 += nwave * 2) {
        const int r = row0 + half;
        // lane covers columns sub*4 .. sub*4+3 ; wave reads 1024 contiguous bytes
        const float4 v = *reinterpret_cast<const float4*>(
            pred + (size_t)r * NCOLS + (size_t)sub * 4);

        // lane-local max of 4 (value only)
        const float bv = fmaxf(fmaxf(v.x, v.y), fmaxf(v.z, v.w));

        // 32-lane value butterfly (masks < 32 stay within each half)
        float mv = bv;
        #pragma unroll
        for (int m = 1; m <= 16; m <<= 1)
            mv = fmaxf(mv, __shfl_xor(mv, m));

        // first lane (lowest sub) holding the max -> earliest column index
        const unsigned long long ball = __ballot(bv == mv);
        const unsigned bmask = half ? (unsigned)(ball >> 32) : (unsigned)ball;
        const int winner = __ffs(bmask) - 1;   // sub-index within this half

        // lane-local first column equal to mv (only meaningful on winner lane)
        const int li = (v.x == mv) ? 0 : (v.y == mv) ? 1 : (v.z == mv) ? 2 : 3;
        const int idx4 = sub * 4 + li;

        const int widx = __shfl(idx4, half * 32 + winner);

        if (sub == 0) {
            const int t = tgt[r];
            int d = widx - t; if (d < 0) d = -d;
            // snap-to-target when |p-t|<=1 -> contribution 0, else |p-t|
            acc += (d <= 1) ? 0 : d;
        }
    }

    if (sub == 0) atomicAdd(&ssum, acc);
    __syncthreads();
    if (threadIdx.x == 0)
        atomicAdd(out, (float)ssum * (1.0f / (float)NROWS));
}

extern "C" void kernel_launch(void* const* d_in, const int* in_sizes, int n_in,
                              void* d_out, int out_size, void* d_ws, size_t ws_size,
                              hipStream_t stream) {
    const float* pred = (const float*)d_in[0];
    const int*   tgt  = (const int*)d_in[1];
    float* out = (float*)d_out;

    // d_out is poisoned 0xAA before every timed launch -> zero it first
    hipMemsetAsync(out, 0, sizeof(float), stream);

    // memory-bound: 2048 blocks (8/CU, full 32-wave occupancy), grid-stride
    const int threads = 256;
    const int blocks  = 2048;
    ordinal_loss_kernel<<<blocks, threads, 0, stream>>>(pred, tgt, out);
}